// Round 4
// baseline (883.228 us; speedup 1.0000x reference)
//
#include <hip/hip_runtime.h>
#include <hip/hip_bf16.h>

// ---------------------------------------------------------------------------
// trimmed SchNet forces on atom 0 via forward-mode AD (3 tangent planes)
// + per-layer 1D lookup table for the edge filter f(d).
//
// State buffers FEAT/XU/AGG use an INTERLEAVED layout [row][plane][128]
// (row stride RS=512 floats): per-edge gathers read one contiguous 2KB
// block instead of 4 plane-scattered 512B rows.
// Plane 0 = value, planes 1..3 = d/dpos[b,0,k].
// Layer 0: x = emb[types]@W1+b1 has 10 distinct rows -> PREM[10][128];
// gather kernels read PREM directly (no l0 GEMM), and the l0 W3-GEMM
// STOREs tangent planes (FEAT tangent enters l0 as zero) so no zero pass.
// GEMMs: plane = blockIdx.y, 64-row M-tiles, K-step 32 (LDS 24.7KB),
// A staged transposed (AsT) for conflict-free b128 fragment reads.
// ---------------------------------------------------------------------------

#define NATC 1024
#define DEGC 32
#define DC   128
#define RC   64
#define LC   3
#define BC   16
#define EC   (NATC*DEGC)            // 32768
#define NAC  (BC*NATC)              // 16384
#define RS   512                    // row stride (4 planes * 128)
#define MTAB 2048
#define DMAXT 20.0f
#define TSLOTS 512

static constexpr size_t PLANE = (size_t)NAC * DC;   // sizing unit (2097152)

__device__ __forceinline__ float sspf(float x) {
    return fmaxf(x, 0.f) + log1pf(expf(-fabsf(x))) - 0.6931471805599453f;
}
__device__ __forceinline__ float sigf(float x) { return 1.f / (1.f + expf(-x)); }

// ---------------------------------------------------------------------------
__global__ void zero_misc(float* out, int* tcnt) {
    int t = threadIdx.x;
    if (t < 48) out[t] = 0.f;
    if (t == 0) *tcnt = 0;
}

__global__ void init_feat(const int* __restrict__ types, const float* __restrict__ emb,
                          float* __restrict__ FEAT) {
    int tid = threadIdx.x;
    int row = blockIdx.x * 2 + (tid >> 7);
    int c = tid & 127;
    FEAT[(size_t)row * RS + c] = emb[types[row] * DC + c];
}

__global__ void build_tlist(const int* __restrict__ ii, const int* __restrict__ jj,
                            int* __restrict__ tcnt, int* __restrict__ tlist) {
    int e = blockIdx.x * 256 + threadIdx.x;
    int s = (ii[e] == 0) - (jj[e] == 0);
    if (s != 0) {
        int p = atomicAdd(tcnt, 1);
        if (p < TSLOTS) tlist[p] = e;
    }
}

__global__ void edge_dist(const float* __restrict__ pos, const int* __restrict__ ii,
                          const int* __restrict__ jj, float* __restrict__ DIST) {
    int g = blockIdx.x * 256 + threadIdx.x;   // 0..B*E-1
    int b = g >> 15;                          // E = 2^15
    int e = g & (EC - 1);
    int i = ii[e], j = jj[e];
    const float* pi = pos + ((size_t)b * NATC + i) * 3;
    const float* pj = pos + ((size_t)b * NATC + j) * 3;
    float dx = pi[0] - pj[0], dy = pi[1] - pj[1], dz = pi[2] - pj[2];
    DIST[g] = sqrtf(fmaf(dx, dx, fmaf(dy, dy, fmaf(dz, dz, 1e-8f))));
}

// PREM[t][c] = (emb[t] @ W1_l0 + b1_l0)[c], 10x128 — one block.
__global__ void prem_k(const float* __restrict__ emb, const float* __restrict__ W1,
                       const float* __restrict__ b1, float* __restrict__ PREM) {
    int tid = threadIdx.x;
    int c = tid & 127;
    int t0 = tid >> 7;                        // 0..1
    for (int q = 0; q < 5; ++q) {
        int t = t0 * 5 + q;
        float acc = b1[c];
        for (int k = 0; k < 128; ++k)
            acc = fmaf(emb[t * 128 + k], W1[k * 128 + c], acc);
        PREM[t * 128 + c] = acc;
    }
}

// ---------------------------------------------------------------------------
// Filter table: TAB[l][m][c] = f(d_m), d_m = m * DMAXT/(MTAB-1).
// One wave per 4 consecutive m-rows (4x weight-traffic reuse).
__global__ __launch_bounds__(256) void build_tables(
    const float* __restrict__ Wf1, const float* __restrict__ bf1,
    const float* __restrict__ Wf2, const float* __restrict__ bf2,
    const float* __restrict__ cen, const float* __restrict__ gam,
    float* __restrict__ TAB) {
    __shared__ float rbf_s[4][4][64];
    __shared__ float a1_s[4][4][128];
    int tid = threadIdx.x, wid = tid >> 6, lane = tid & 63;
    int g = blockIdx.x * 4 + wid;             // row-group, total 3*MTAB/4
    int l = g / (MTAB / 4);
    int mb = (g % (MTAB / 4)) * 4;
    float gm = gam[l * RC + lane], cc = cen[l * RC + lane];
#pragma unroll
    for (int row = 0; row < 4; ++row) {
        float d = (float)(mb + row) * (DMAXT / (MTAB - 1));
        float t = d - cc;
        rbf_s[wid][row][lane] = expf(-gm * t * t);
    }
    __syncthreads();
    float t1a[4], t1b[4];
#pragma unroll
    for (int row = 0; row < 4; ++row) { t1a[row] = bf1[l * DC + lane]; t1b[row] = bf1[l * DC + 64 + lane]; }
    const float* w1 = Wf1 + (size_t)l * RC * DC;
    for (int r = 0; r < 64; ++r) {
        float wa = w1[r * DC + lane], wb = w1[r * DC + 64 + lane];
#pragma unroll
        for (int row = 0; row < 4; ++row) {
            float rv = rbf_s[wid][row][r];
            t1a[row] = fmaf(rv, wa, t1a[row]); t1b[row] = fmaf(rv, wb, t1b[row]);
        }
    }
#pragma unroll
    for (int row = 0; row < 4; ++row) {
        a1_s[wid][row][lane] = sspf(t1a[row]);
        a1_s[wid][row][64 + lane] = sspf(t1b[row]);
    }
    __syncthreads();
    float t2a[4], t2b[4];
#pragma unroll
    for (int row = 0; row < 4; ++row) { t2a[row] = bf2[l * DC + lane]; t2b[row] = bf2[l * DC + 64 + lane]; }
    const float* w2 = Wf2 + (size_t)l * DC * DC;
    for (int mm = 0; mm < 128; ++mm) {
        float wa = w2[mm * DC + lane], wb = w2[mm * DC + 64 + lane];
#pragma unroll
        for (int row = 0; row < 4; ++row) {
            float av = a1_s[wid][row][mm];
            t2a[row] = fmaf(av, wa, t2a[row]); t2b[row] = fmaf(av, wb, t2b[row]);
        }
    }
#pragma unroll
    for (int row = 0; row < 4; ++row) {
        float* trow = TAB + ((size_t)l * MTAB + mb + row) * DC;
        trow[lane] = sspf(t2a[row]);
        trow[64 + lane] = sspf(t2b[row]);
    }
}

// ---------------------------------------------------------------------------
// Per-plane GEMM (plane = blockIdx.y): OUT[:, p] = op(IN[:, p] @ W (+bias p0)).
// Rows strided RS. M-tile 64, N=128, K-step 32; A staged transposed.
// AMODE 0: A = IN.  AMODE 1: A = p==0 ? ssp(T0) : sigf(T0)*Tp (T0 = plane 0).
// WMODE 0: store (+bias p0).  WMODE 1: += (+bias p0).
// WMODE 2: p0 += (+bias); p>=1 store (layer-0: FEAT tangent starts at 0).
template <int AMODE, int WMODE>
__global__ __launch_bounds__(256) void gemmP(
    const float* __restrict__ IN, const float* __restrict__ W,
    const float* __restrict__ bias, float* __restrict__ OUT) {
    __shared__ float Bs[32][128];
    __shared__ float AsT[32][68];
    const int tid = threadIdx.x;
    const int tx = tid & 15, ty = tid >> 4;
    const int row0 = blockIdx.x * 64;
    const int p = blockIdx.y;
    float acc[4][8] = {};
    for (int kq = 0; kq < 4; ++kq) {
        __syncthreads();
#pragma unroll
        for (int rep = 0; rep < 4; ++rep) {               // Bs: 32x128
            int i4 = rep * 256 + tid;
            int r = i4 >> 5, c4 = i4 & 31;
            *(float4*)&Bs[r][c4 * 4] = *(const float4*)&W[(kq * 32 + r) * DC + c4 * 4];
        }
#pragma unroll
        for (int rep = 0; rep < 2; ++rep) {               // AsT: 64 rows x 32 k
            int i4 = rep * 256 + tid;
            int r = i4 >> 3, c4 = i4 & 7;
            int col = kq * 32 + c4 * 4;
            size_t rbase = (size_t)(row0 + r) * RS;
            float4 v = *(const float4*)&IN[rbase + p * DC + col];
            if (AMODE == 1) {
                if (p == 0) {
                    v.x = sspf(v.x); v.y = sspf(v.y); v.z = sspf(v.z); v.w = sspf(v.w);
                } else {
                    float4 v0 = *(const float4*)&IN[rbase + col];
                    v.x *= sigf(v0.x); v.y *= sigf(v0.y); v.z *= sigf(v0.z); v.w *= sigf(v0.w);
                }
            }
            AsT[c4 * 4 + 0][r] = v.x; AsT[c4 * 4 + 1][r] = v.y;
            AsT[c4 * 4 + 2][r] = v.z; AsT[c4 * 4 + 3][r] = v.w;
        }
        __syncthreads();
#pragma unroll
        for (int kk = 0; kk < 32; ++kk) {
            float a[4], bl[8];
            *(float4*)&a[0] = *(const float4*)&AsT[kk][ty * 4];
            *(float4*)&bl[0] = *(const float4*)&Bs[kk][tx * 4];
            *(float4*)&bl[4] = *(const float4*)&Bs[kk][64 + tx * 4];
#pragma unroll
            for (int i = 0; i < 4; ++i)
#pragma unroll
                for (int j = 0; j < 8; ++j) acc[i][j] = fmaf(a[i], bl[j], acc[i][j]);
        }
    }
#pragma unroll
    for (int i = 0; i < 4; ++i) {
        int grow = row0 + ty * 4 + i;
        float* ob = OUT + (size_t)grow * RS + p * DC;
        float4 vlo, vhi;
        vlo.x = acc[i][0]; vlo.y = acc[i][1]; vlo.z = acc[i][2]; vlo.w = acc[i][3];
        vhi.x = acc[i][4]; vhi.y = acc[i][5]; vhi.z = acc[i][6]; vhi.w = acc[i][7];
        if (WMODE == 0) {
            if (p == 0) {
                const float4 blo = *(const float4*)&bias[tx * 4];
                const float4 bhi = *(const float4*)&bias[64 + tx * 4];
                vlo.x += blo.x; vlo.y += blo.y; vlo.z += blo.z; vlo.w += blo.w;
                vhi.x += bhi.x; vhi.y += bhi.y; vhi.z += bhi.z; vhi.w += bhi.w;
            }
        } else if (WMODE == 1 || (WMODE == 2 && p == 0)) {
            const float4 olo = *(const float4*)&ob[tx * 4];
            const float4 ohi = *(const float4*)&ob[64 + tx * 4];
            vlo.x += olo.x; vlo.y += olo.y; vlo.z += olo.z; vlo.w += olo.w;
            vhi.x += ohi.x; vhi.y += ohi.y; vhi.z += ohi.z; vhi.w += ohi.w;
            if (p == 0) {
                const float4 blo = *(const float4*)&bias[tx * 4];
                const float4 bhi = *(const float4*)&bias[64 + tx * 4];
                vlo.x += blo.x; vlo.y += blo.y; vlo.z += blo.z; vlo.w += blo.w;
                vhi.x += bhi.x; vhi.y += bhi.y; vhi.z += bhi.z; vhi.w += bhi.w;
            }
        }
        *(float4*)&ob[tx * 4] = vlo;
        *(float4*)&ob[64 + tx * 4] = vhi;
    }
}

// ---------------------------------------------------------------------------
// Per-atom aggregation: AGG[i][p] = sum_e f_tab(d_e) * x_p[j_e].
// One wave per (b,atom); lane owns cols {2*lane, 2*lane+1}. Interleaved rows:
// the 4-plane gather for one edge is one contiguous 2KB block.
// L0: x0 row = PREM[types[b,j]], tangent planes -> zeros.
template <int L0>
__global__ __launch_bounds__(256) void filter_agg(
    const float* __restrict__ X, const float* __restrict__ TABl,
    const float* __restrict__ DIST, const int* __restrict__ jj,
    const int* __restrict__ types, const float* __restrict__ PREM,
    float* __restrict__ AGG) {
    int tid = threadIdx.x, wid = tid >> 6, lane = tid & 63;
    int rowg = blockIdx.x * 4 + wid;          // 0..NAC-1
    int b = rowg >> 10, i = rowg & (NATC - 1);
    int c0 = lane * 2;
    float a0x = 0, a0y = 0, a1x = 0, a1y = 0, a2x = 0, a2y = 0, a3x = 0, a3y = 0;
    const float invh = (float)(MTAB - 1) / DMAXT;
    const float* distb = DIST + (size_t)b * EC;
    for (int k = 0; k < 32; ++k) {
        int e = (i << 5) + k;
        float dd = distb[e];
        int j = jj[e];
        float u = fminf(dd * invh, (float)(MTAB - 1) - 0.001f);
        int iu = (int)u;
        float w = u - (float)iu;
        const float2 lo = *(const float2*)&TABl[(size_t)iu * DC + c0];
        const float2 hi = *(const float2*)&TABl[(size_t)(iu + 1) * DC + c0];
        float f0 = fmaf(w, hi.x - lo.x, lo.x);
        float f1 = fmaf(w, hi.y - lo.y, lo.y);
        if (L0) {
            const float2 x0 = *(const float2*)&PREM[(size_t)types[b * NATC + j] * DC + c0];
            a0x = fmaf(f0, x0.x, a0x); a0y = fmaf(f1, x0.y, a0y);
        } else {
            size_t xb = (size_t)(b * NATC + j) * RS + c0;
            float2 x0 = *(const float2*)&X[xb];
            float2 x1 = *(const float2*)&X[xb + 128];
            float2 x2 = *(const float2*)&X[xb + 256];
            float2 x3 = *(const float2*)&X[xb + 384];
            a0x = fmaf(f0, x0.x, a0x); a0y = fmaf(f1, x0.y, a0y);
            a1x = fmaf(f0, x1.x, a1x); a1y = fmaf(f1, x1.y, a1y);
            a2x = fmaf(f0, x2.x, a2x); a2y = fmaf(f1, x2.y, a2y);
            a3x = fmaf(f0, x3.x, a3x); a3y = fmaf(f1, x3.y, a3y);
        }
    }
    size_t ob = (size_t)rowg * RS + c0;
    *(float2*)&AGG[ob] = make_float2(a0x, a0y);
    *(float2*)&AGG[ob + 128] = make_float2(a1x, a1y);
    *(float2*)&AGG[ob + 256] = make_float2(a2x, a2y);
    *(float2*)&AGG[ob + 384] = make_float2(a3x, a3y);
}

// ---------------------------------------------------------------------------
// Exact filter + d-derivative for edges touching atom 0; scatters
// x0[b,j] * f'(d) * (s*disp_k/d) into the tangent AGG planes.
template <int L0>
__global__ __launch_bounds__(256) void tangent_filter(
    const float* __restrict__ pos, const int* __restrict__ ii, const int* __restrict__ jj,
    const float* __restrict__ Wf1l, const float* __restrict__ bf1l,
    const float* __restrict__ Wf2l, const float* __restrict__ bf2l,
    const float* __restrict__ cenl, const float* __restrict__ gaml,
    const float* __restrict__ X, const int* __restrict__ types,
    const float* __restrict__ PREM, float* __restrict__ AGG,
    const int* __restrict__ tcnt, const int* __restrict__ tlist) {
    __shared__ float sh[4][384];
    int tid = threadIdx.x, wid = tid >> 6, lane = tid & 63;
    int rowg = blockIdx.x * 4 + wid;
    int b = rowg >> 9;                        // TSLOTS = 512
    int slot = rowg & (TSLOTS - 1);
    int n = *tcnt; n = n > TSLOTS ? TSLOTS : n;
    bool active = slot < n;
    int e = active ? tlist[slot] : 0;
    int i = ii[e], j = jj[e];
    const float* pi = pos + ((size_t)b * NATC + i) * 3;
    const float* pj = pos + ((size_t)b * NATC + j) * 3;
    float dx = pi[0] - pj[0], dy = pi[1] - pj[1], dz = pi[2] - pj[2];
    float d = sqrtf(fmaf(dx, dx, fmaf(dy, dy, fmaf(dz, dz, 1e-8f))));
    float s = (float)((i == 0) - (j == 0));
    float inv_d = s / d;
    float sd0 = dx * inv_d, sd1 = dy * inv_d, sd2 = dz * inv_d;
    float g = gaml[lane], c = cenl[lane];
    float t = d - c;
    float rb = expf(-g * t * t);
    float db = -2.f * g * t * rb;
    sh[wid][lane] = rb;
    sh[wid][64 + lane] = db;
    __syncthreads();
    float t1a = bf1l[lane], t1b = bf1l[64 + lane], g1a = 0, g1b = 0;
    for (int r = 0; r < 64; ++r) {
        float rv = sh[wid][r], dv = sh[wid][64 + r];
        float wa = Wf1l[r * DC + lane], wb = Wf1l[r * DC + 64 + lane];
        t1a = fmaf(rv, wa, t1a); t1b = fmaf(rv, wb, t1b);
        g1a = fmaf(dv, wa, g1a); g1b = fmaf(dv, wb, g1b);
    }
    __syncthreads();
    sh[wid][128 + lane] = sspf(t1a);
    sh[wid][192 + lane] = sspf(t1b);
    sh[wid][256 + lane] = sigf(t1a) * g1a;
    sh[wid][320 + lane] = sigf(t1b) * g1b;
    __syncthreads();
    float t2a = bf2l[lane], t2b = bf2l[64 + lane], gba = 0, gbb = 0;
    for (int mm = 0; mm < 128; ++mm) {
        float av = sh[wid][128 + mm], gv = sh[wid][256 + mm];
        float wa = Wf2l[mm * DC + lane], wb = Wf2l[mm * DC + 64 + lane];
        t2a = fmaf(av, wa, t2a); t2b = fmaf(av, wb, t2b);
        gba = fmaf(gv, wa, gba); gbb = fmaf(gv, wb, gbb);
    }
    const float* xrow = L0 ? (PREM + (size_t)types[b * NATC + j] * DC)
                           : (X + (size_t)(b * NATC + j) * RS);
    float ma = sigf(t2a) * gba * xrow[lane];
    float mb = sigf(t2b) * gbb * xrow[64 + lane];
    if (active) {
        size_t ob = (size_t)(b * NATC + i) * RS;
        atomicAdd(&AGG[ob + 128 + lane], sd0 * ma);
        atomicAdd(&AGG[ob + 128 + 64 + lane], sd0 * mb);
        atomicAdd(&AGG[ob + 256 + lane], sd1 * ma);
        atomicAdd(&AGG[ob + 256 + 64 + lane], sd1 * mb);
        atomicAdd(&AGG[ob + 384 + lane], sd2 * ma);
        atomicAdd(&AGG[ob + 384 + 64 + lane], sd2 * mb);
    }
}

// ---------------------------------------------------------------------------
// Readout: force[b,k] = -sum_a sigmoid(t4)*(featdot_k @ Wd) . We
__global__ __launch_bounds__(256) void readout(
    const float* __restrict__ FEAT, const float* __restrict__ Wd,
    const float* __restrict__ bd, const float* __restrict__ We,
    float* __restrict__ out) {
    __shared__ float red[4][3];
    int tid = threadIdx.x, wid = tid >> 6, lane = tid & 63;
    int rowg = blockIdx.x * 4 + wid;          // 0..NAC-1
    int b = rowg >> 10;
    const float* f0p = FEAT + (size_t)rowg * RS;
    float t4 = bd[lane], w0 = 0, w1 = 0, w2 = 0;
    for (int cc = 0; cc < 128; ++cc) {
        float wd = Wd[cc * 64 + lane];
        t4 = fmaf(f0p[cc], wd, t4);
        w0 = fmaf(f0p[128 + cc], wd, w0);
        w1 = fmaf(f0p[256 + cc], wd, w1);
        w2 = fmaf(f0p[384 + cc], wd, w2);
    }
    float s4 = sigf(t4) * We[lane];
    float v0 = s4 * w0, v1 = s4 * w1, v2 = s4 * w2;
#pragma unroll
    for (int off = 32; off > 0; off >>= 1) {
        v0 += __shfl_down(v0, off);
        v1 += __shfl_down(v1, off);
        v2 += __shfl_down(v2, off);
    }
    if (lane == 0) { red[wid][0] = v0; red[wid][1] = v1; red[wid][2] = v2; }
    __syncthreads();
    if (tid < 3) {
        float sum = red[0][tid] + red[1][tid] + red[2][tid] + red[3][tid];
        atomicAdd(&out[b * 3 + tid], -sum);
    }
}

// ---------------------------------------------------------------------------
extern "C" void kernel_launch(void* const* d_in, const int* in_sizes, int n_in,
                              void* d_out, int out_size, void* d_ws, size_t ws_size,
                              hipStream_t stream) {
    const float* pos   = (const float*)d_in[0];
    const int*   types = (const int*)d_in[1];
    const int*   ii    = (const int*)d_in[2];
    const int*   jj    = (const int*)d_in[3];
    // d_in[4] = seg_i == idx_i (unused; segments are [32i, 32i+32))
    const float* emb = (const float*)d_in[5];
    const float* W1  = (const float*)d_in[6];
    const float* b1  = (const float*)d_in[7];
    const float* Wf1 = (const float*)d_in[8];
    const float* bf1 = (const float*)d_in[9];
    const float* Wf2 = (const float*)d_in[10];
    const float* bf2 = (const float*)d_in[11];
    const float* W2  = (const float*)d_in[12];
    const float* b2  = (const float*)d_in[13];
    const float* W3  = (const float*)d_in[14];
    const float* b3  = (const float*)d_in[15];
    const float* cen = (const float*)d_in[16];
    const float* gam = (const float*)d_in[17];
    const float* Wd  = (const float*)d_in[18];
    const float* bd  = (const float*)d_in[19];
    const float* We  = (const float*)d_in[20];
    float* out = (float*)d_out;
    float* ws  = (float*)d_ws;

    float* FEAT = ws;                          // [NAC][4][128] interleaved
    float* XU   = ws + 4 * PLANE;
    float* AGG  = ws + 8 * PLANE;
    float* TAB  = ws + 12 * PLANE;
    float* DIST = TAB + (size_t)LC * MTAB * DC;
    float* PREM = DIST + (size_t)BC * EC;
    int*   ints = (int*)(PREM + 10 * DC);
    int* tcnt = ints;
    int* tlist = ints + 1;

    zero_misc<<<1, 64, 0, stream>>>(out, tcnt);
    init_feat<<<NAC / 2, 256, 0, stream>>>(types, emb, FEAT);
    build_tlist<<<EC / 256, 256, 0, stream>>>(ii, jj, tcnt, tlist);
    edge_dist<<<(BC * EC) / 256, 256, 0, stream>>>(pos, ii, jj, DIST);
    build_tables<<<(LC * MTAB) / 16, 256, 0, stream>>>(Wf1, bf1, Wf2, bf2, cen, gam, TAB);
    prem_k<<<1, 256, 0, stream>>>(emb, W1, b1, PREM);

    const dim3 gp(NAC / 64, 4);
    for (int l = 0; l < LC; ++l) {
        const float* TABl = TAB + (size_t)l * MTAB * DC;
        if (l == 0) {
            filter_agg<1><<<NAC / 4, 256, 0, stream>>>(XU, TABl, DIST, jj, types, PREM, AGG);
            tangent_filter<1><<<(BC * TSLOTS) / 4, 256, 0, stream>>>(
                pos, ii, jj, Wf1, bf1, Wf2, bf2, cen, gam, XU, types, PREM, AGG, tcnt, tlist);
            gemmP<0, 0><<<gp, 256, 0, stream>>>(AGG, W2, b2, XU);
            gemmP<1, 2><<<gp, 256, 0, stream>>>(XU, W3, b3, FEAT);
        } else {
            gemmP<0, 0><<<gp, 256, 0, stream>>>(FEAT, W1 + l * DC * DC, b1 + l * DC, XU);
            filter_agg<0><<<NAC / 4, 256, 0, stream>>>(XU, TABl, DIST, jj, types, PREM, AGG);
            tangent_filter<0><<<(BC * TSLOTS) / 4, 256, 0, stream>>>(
                pos, ii, jj, Wf1 + l * RC * DC, bf1 + l * DC, Wf2 + l * DC * DC, bf2 + l * DC,
                cen + l * RC, gam + l * RC, XU, types, PREM, AGG, tcnt, tlist);
            gemmP<0, 0><<<gp, 256, 0, stream>>>(AGG, W2 + l * DC * DC, b2 + l * DC, XU);
            gemmP<1, 1><<<gp, 256, 0, stream>>>(XU, W3 + l * DC * DC, b3 + l * DC, FEAT);
        }
    }
    readout<<<NAC / 4, 256, 0, stream>>>(FEAT, Wd, bd, We, out);
}